// Round 2
// baseline (369.852 us; speedup 1.0000x reference)
//
#include <hip/hip_runtime.h>

// Newton-Schulz matrix sqrt, 1024 batches of 128x128 SPD, 5 iterations.
// One workgroup per batch; Y/Z resident in LDS as split-bf16 (hi+lo) pairs;
// T staged transposed through a 32-row quarter panel. All B-operands read
// row-wise via symmetry (all iterates are symmetric polynomials in A).
// 3-term split product (hihi + hilo + lohi) gives ~2^-17 relative matmul error.
//
// R2 fix: init loader covered only 32 of 128 rows (4096 of 16384 floats) ->
// uninitialized LDS fed MFMAs -> NaN. Now each thread loads 64 floats and A is
// stored UNNORMALIZED; 1/normA is folded into iteration 1 (T1 and Y1 scaling).

#define NN 128
#define S  136   // row stride in shorts for Y/Z (pad 8: bank-uniform, 16B rows)
#define SQ 40    // row stride in shorts for Tq panel (32 + 8)

typedef short bf16x8  __attribute__((ext_vector_type(8)));
typedef short short4v __attribute__((ext_vector_type(4)));
typedef float f32x4   __attribute__((ext_vector_type(4)));

__device__ __forceinline__ float bf2f(short h) {
  union { unsigned u; float f; } c;
  c.u = ((unsigned)(unsigned short)h) << 16;
  return c.f;
}

__device__ __forceinline__ short f2bf(float x) {
  union { float f; unsigned u; } c; c.f = x;
  unsigned u = c.u;
  return (short)((u + 0x7fffu + ((u >> 16) & 1u)) >> 16);   // RNE to bf16
}

__device__ __forceinline__ void split_bf16(float x, short& h, short& l) {
  h = f2bf(x);
  l = f2bf(x - bf2f(h));
}

#define MFMA3(ACC, AH, AL, BH, BL)                                        \
  ACC = __builtin_amdgcn_mfma_f32_16x16x32_bf16(AH, BH, ACC, 0, 0, 0);    \
  ACC = __builtin_amdgcn_mfma_f32_16x16x32_bf16(AH, BL, ACC, 0, 0, 0);    \
  ACC = __builtin_amdgcn_mfma_f32_16x16x32_bf16(AL, BH, ACC, 0, 0, 0);

__global__ __launch_bounds__(256, 1)
void ns_sqrt_kernel(const float* __restrict__ A, float* __restrict__ out) {
  __shared__ __align__(16) short Yhi[NN * S];
  __shared__ __align__(16) short Ylo[NN * S];
  __shared__ __align__(16) short Zhi[NN * S];
  __shared__ __align__(16) short Zlo[NN * S];
  __shared__ __align__(16) short Tqhi[NN * SQ];
  __shared__ __align__(16) short Tqlo[NN * SQ];
  __shared__ float red[8];

  const int tid  = threadIdx.x;
  const int wave = tid >> 6;
  const int lane = tid & 63;
  const int quad = lane >> 4;     // 0..3, selects k-octet (A/B) / row group (C/D)
  const int lrow = lane & 15;     // row (A) / col (B, C/D) within tile
  const int qr = wave >> 1, qc = wave & 1;
  const int RB = qr << 6, CB = qc << 6;   // 64x64 quadrant base
  const int b = blockIdx.x;
  const float* Ab = A + (size_t)b * (NN * NN);

  // ---------- init: load ALL of A (64 floats/thread), Frobenius sum, ----------
  // ---------- store UNNORMALIZED split-bf16 A into Y                 ----------
  float ss = 0.f;
  {
    const float4* p = reinterpret_cast<const float4*>(Ab);
    const int r0 = tid >> 3;          // 0..31
    const int c4 = (tid & 7) << 2;    // float4 col index: 0..28 step 4
    const int c0 = c4 << 2;           // short col base: 0..112 step 16
    #pragma unroll
    for (int rb = 0; rb < 4; ++rb) {
      const int row = r0 + (rb << 5);
      bf16x8 vh[2], vl[2];
      #pragma unroll
      for (int q = 0; q < 4; ++q) {
        float4 v = p[row * (NN / 4) + c4 + q];
        float xs[4] = {v.x, v.y, v.z, v.w};
        #pragma unroll
        for (int e = 0; e < 4; ++e) {
          float x = xs[e];
          ss += x * x;
          short hh, ll; split_bf16(x, hh, ll);
          vh[q >> 1][((q & 1) << 2) + e] = hh;
          vl[q >> 1][((q & 1) << 2) + e] = ll;
        }
      }
      *(bf16x8*)&Yhi[row * S + c0]     = vh[0];
      *(bf16x8*)&Yhi[row * S + c0 + 8] = vh[1];
      *(bf16x8*)&Ylo[row * S + c0]     = vl[0];
      *(bf16x8*)&Ylo[row * S + c0 + 8] = vl[1];
    }
  }
  #pragma unroll
  for (int off = 32; off; off >>= 1) ss += __shfl_xor(ss, off, 64);
  if (lane == 0) red[wave] = ss;
  __syncthreads();
  const float normA = sqrtf(red[0] + red[1] + red[2] + red[3]);
  const float rn    = 1.f / normA;
  const float s_out = sqrtf(normA);

  f32x4 accM[4][4];
  const f32x4 zero4 = {0.f, 0.f, 0.f, 0.f};

  #pragma unroll 1
  for (int it = 1; it <= 5; ++it) {
    const bool doQ = (it >= 2) && (it <= 4);   // it1: Z1 = T; it5: Z unused
    f32x4 accP[4][4];
    f32x4 accQ[4][4];
    #pragma unroll
    for (int i = 0; i < 4; ++i)
      #pragma unroll
      for (int j = 0; j < 4; ++j) { accP[i][j] = zero4; accQ[i][j] = zero4; }

    if (it == 1) {
      // M = Z0*Y0n, with stored Y = A (unnormalized): accM = A quadrant.
      #pragma unroll
      for (int i = 0; i < 4; ++i)
        #pragma unroll
        for (int j = 0; j < 4; ++j) {
          const int col  = CB + 16*j + lrow;
          const int row0 = RB + 16*i + (quad << 2);
          short4v h = *(const short4v*)&Yhi[col * S + row0];  // symmetric read
          short4v l = *(const short4v*)&Ylo[col * S + row0];
          #pragma unroll
          for (int r = 0; r < 4; ++r) accM[i][j][r] = bf2f(h[r]) + bf2f(l[r]);
        }
    } else {
      // M = Z*Y  (A = Z rows; B = Y rows via symmetry)
      #pragma unroll
      for (int i = 0; i < 4; ++i)
        #pragma unroll
        for (int j = 0; j < 4; ++j) accM[i][j] = zero4;
      #pragma unroll
      for (int kc = 0; kc < 4; ++kc) {
        const int k0 = (kc << 5) + (quad << 3);
        bf16x8 ah[4], al[4], bh[4], bl[4];
        #pragma unroll
        for (int i = 0; i < 4; ++i) {
          const int o = (RB + lrow + 16*i) * S + k0;
          ah[i] = *(const bf16x8*)&Zhi[o];
          al[i] = *(const bf16x8*)&Zlo[o];
        }
        #pragma unroll
        for (int j = 0; j < 4; ++j) {
          const int o = (CB + lrow + 16*j) * S + k0;
          bh[j] = *(const bf16x8*)&Yhi[o];
          bl[j] = *(const bf16x8*)&Ylo[o];
        }
        #pragma unroll
        for (int i = 0; i < 4; ++i)
          #pragma unroll
          for (int j = 0; j < 4; ++j) { MFMA3(accM[i][j], ah[i], al[i], bh[j], bl[j]); }
      }
    }

    // T = 1.5 I - 0.5 * mscale * M   (mscale folds the it==1 normalization)
    const float mscale = (it == 1) ? rn : 1.0f;
    #pragma unroll
    for (int i = 0; i < 4; ++i)
      #pragma unroll
      for (int j = 0; j < 4; ++j)
        #pragma unroll
        for (int r = 0; r < 4; ++r) {
          float tv = -0.5f * mscale * accM[i][j][r];
          if (RB + 16*i + (quad << 2) + r == CB + 16*j + lrow) tv += 1.5f;
          accM[i][j][r] = tv;
        }

    // 4 phases over 32-row blocks of T, staged transposed into Tq
    #pragma unroll
    for (int t = 0; t < 4; ++t) {
      __syncthreads();                     // Tq free from previous phase
      if (qr == (t >> 1)) {
        #pragma unroll
        for (int ii = 0; ii < 2; ++ii) {
          const int i   = ((t & 1) << 1) + ii;
          const int kp0 = (ii << 4) + (quad << 2);   // row0 - 32t
          #pragma unroll
          for (int j = 0; j < 4; ++j) {
            const int col = CB + 16*j + lrow;
            short4v h, l;
            #pragma unroll
            for (int r = 0; r < 4; ++r) {
              short hh, ll;
              split_bf16(accM[i][j][r], hh, ll);
              h[r] = hh; l[r] = ll;
            }
            *(short4v*)&Tqhi[col * SQ + kp0] = h;   // Tq[c][k'] = T[32t+k'][c]
            *(short4v*)&Tqlo[col * SQ + kp0] = l;
          }
        }
      }
      __syncthreads();
      {
        const int k0 = (t << 5) + (quad << 3);
        const int kq = quad << 3;
        bf16x8 ah[4], al[4], bh[4], bl[4];
        // P += Ystored[:,32t:32t+32] * T[32t:32t+32,:]
        #pragma unroll
        for (int i = 0; i < 4; ++i) {
          const int o = (RB + lrow + 16*i) * S + k0;
          ah[i] = *(const bf16x8*)&Yhi[o];
          al[i] = *(const bf16x8*)&Ylo[o];
        }
        #pragma unroll
        for (int j = 0; j < 4; ++j) {
          const int o = (CB + lrow + 16*j) * SQ + kq;   // B[k][n] = Tq[n][k']
          bh[j] = *(const bf16x8*)&Tqhi[o];
          bl[j] = *(const bf16x8*)&Tqlo[o];
        }
        #pragma unroll
        for (int i = 0; i < 4; ++i)
          #pragma unroll
          for (int j = 0; j < 4; ++j) { MFMA3(accP[i][j], ah[i], al[i], bh[j], bl[j]); }
        if (doQ) {
          // Q += T[:,32t:32t+32] * Z[32t:32t+32,:]
          #pragma unroll
          for (int i = 0; i < 4; ++i) {
            const int o = (RB + lrow + 16*i) * SQ + kq;  // A[m][k] = Tq[m][k'] (T sym)
            ah[i] = *(const bf16x8*)&Tqhi[o];
            al[i] = *(const bf16x8*)&Tqlo[o];
          }
          #pragma unroll
          for (int j = 0; j < 4; ++j) {
            const int o = (CB + lrow + 16*j) * S + k0;   // B via Z symmetry
            bh[j] = *(const bf16x8*)&Zhi[o];
            bl[j] = *(const bf16x8*)&Zlo[o];
          }
          #pragma unroll
          for (int i = 0; i < 4; ++i)
            #pragma unroll
            for (int j = 0; j < 4; ++j) { MFMA3(accQ[i][j], ah[i], al[i], bh[j], bl[j]); }
        }
      }
    }
    __syncthreads();   // all reads of Y/Z/Tq complete

    if (it < 5) {
      // write-back (transposed store = symmetric, enables packed b64 writes)
      // it==1: true Y1 = rn * (A*T)  (normalization fold)
      const float yscale = (it == 1) ? rn : 1.0f;
      #pragma unroll
      for (int i = 0; i < 4; ++i)
        #pragma unroll
        for (int j = 0; j < 4; ++j) {
          const int col  = CB + 16*j + lrow;
          const int row0 = RB + 16*i + (quad << 2);
          short4v h, l;
          #pragma unroll
          for (int r = 0; r < 4; ++r) {
            short hh, ll; split_bf16(yscale * accP[i][j][r], hh, ll);
            h[r] = hh; l[r] = ll;
          }
          *(short4v*)&Yhi[col * S + row0] = h;
          *(short4v*)&Ylo[col * S + row0] = l;
          #pragma unroll
          for (int r = 0; r < 4; ++r) {
            const float zv = (it == 1) ? accM[i][j][r] : accQ[i][j][r];
            short hh, ll; split_bf16(zv, hh, ll);
            h[r] = hh; l[r] = ll;
          }
          *(short4v*)&Zhi[col * S + row0] = h;
          *(short4v*)&Zlo[col * S + row0] = l;
        }
      __syncthreads();
    } else {
      // final: out = Y5 * sqrt(normA)
      float* ob = out + (size_t)b * (NN * NN);
      #pragma unroll
      for (int i = 0; i < 4; ++i)
        #pragma unroll
        for (int j = 0; j < 4; ++j) {
          const int col  = CB + 16*j + lrow;
          const int row0 = RB + 16*i + (quad << 2);
          #pragma unroll
          for (int r = 0; r < 4; ++r)
            ob[(size_t)(row0 + r) * NN + col] = accP[i][j][r] * s_out;
        }
    }
  }
}

extern "C" void kernel_launch(void* const* d_in, const int* in_sizes, int n_in,
                              void* d_out, int out_size, void* d_ws, size_t ws_size,
                              hipStream_t stream) {
  const float* A = (const float*)d_in[0];
  float* out = (float*)d_out;
  ns_sqrt_kernel<<<dim3(1024), dim3(256), 0, stream>>>(A, out);
}

// Round 3
// 330.530 us; speedup vs baseline: 1.1190x; 1.1190x over previous
//
#include <hip/hip_runtime.h>

// Newton-Schulz matrix sqrt, 1024 batches of 128x128 SPD, 5 iterations.
// R3: 512 threads / 8 waves per WG (32x64 output slab per wave, 2x4 tiles).
//   - halves per-wave accumulator set (96 regs) -> kills the R2 scratch spills
//     (VGPR was 256 + 68 MB spill stores; WRITE_SIZE 135 MB vs 67 MB output)
//   - 2 waves/SIMD doubles latency hiding (Occupancy 11.4% -> ~23%)
//   - Z update computed as Z*T (== T*Z, commuting family) so P=Y*T and Q=Z*T
//     share the Tq B-fragments -> 33% fewer LDS reads in the PQ phases.
// Y/Z resident in LDS as split-bf16 (hi+lo); T staged via a 32-k' panel (Tq),
// stored "transposed" (packed b64) which is the same matrix since T symmetric.
// 3-term split product (hihi + hilo + lohi) ~2^-17 relative matmul error.

#define NN 128
#define S  136   // row stride in shorts for Y/Z (pad 8: bank-balanced, 16B rows)
#define SQ 40    // row stride in shorts for Tq panel (32 + 8)

typedef short bf16x8  __attribute__((ext_vector_type(8)));
typedef short short4v __attribute__((ext_vector_type(4)));
typedef float f32x4   __attribute__((ext_vector_type(4)));

__device__ __forceinline__ float bf2f(short h) {
  union { unsigned u; float f; } c;
  c.u = ((unsigned)(unsigned short)h) << 16;
  return c.f;
}

__device__ __forceinline__ short f2bf(float x) {
  union { float f; unsigned u; } c; c.f = x;
  unsigned u = c.u;
  return (short)((u + 0x7fffu + ((u >> 16) & 1u)) >> 16);   // RNE to bf16
}

__device__ __forceinline__ void split_bf16(float x, short& h, short& l) {
  h = f2bf(x);
  l = f2bf(x - bf2f(h));
}

#define MFMA3(ACC, AH, AL, BH, BL)                                        \
  ACC = __builtin_amdgcn_mfma_f32_16x16x32_bf16(AH, BH, ACC, 0, 0, 0);    \
  ACC = __builtin_amdgcn_mfma_f32_16x16x32_bf16(AH, BL, ACC, 0, 0, 0);    \
  ACC = __builtin_amdgcn_mfma_f32_16x16x32_bf16(AL, BH, ACC, 0, 0, 0);

__global__ __launch_bounds__(512, 1)
void ns_sqrt_kernel(const float* __restrict__ A, float* __restrict__ out) {
  __shared__ __align__(16) short Yhi[NN * S];
  __shared__ __align__(16) short Ylo[NN * S];
  __shared__ __align__(16) short Zhi[NN * S];
  __shared__ __align__(16) short Zlo[NN * S];
  __shared__ __align__(16) short Tqhi[NN * SQ];
  __shared__ __align__(16) short Tqlo[NN * SQ];
  __shared__ float red[8];

  const int tid  = threadIdx.x;
  const int wave = tid >> 6;
  const int lane = tid & 63;
  const int quad = lane >> 4;     // k-octet (A/B) / row group (C/D)
  const int lrow = lane & 15;     // row (A) / col (B, C/D) within tile
  const int wr = wave >> 1, wc = wave & 1;
  const int RB = wr << 5, CB = wc << 6;   // 32x64 slab base
  const int b = blockIdx.x;
  const float* Ab = A + (size_t)b * (NN * NN);

  // ---------- init: load all of A (32 floats/thread), Frobenius sum, ----------
  // ---------- store UNNORMALIZED split-bf16 A into Y                 ----------
  float ss = 0.f;
  {
    const float4* p = reinterpret_cast<const float4*>(Ab);
    const int row = tid >> 2;          // 0..127
    const int c0  = (tid & 3) << 5;    // short/float col base: 0,32,64,96
    #pragma unroll
    for (int ch = 0; ch < 4; ++ch) {
      bf16x8 vh, vl;
      #pragma unroll
      for (int q = 0; q < 2; ++q) {
        float4 v = p[row * (NN / 4) + (c0 >> 2) + (ch << 1) + q];
        float xs[4] = {v.x, v.y, v.z, v.w};
        #pragma unroll
        for (int e = 0; e < 4; ++e) {
          float x = xs[e];
          ss += x * x;
          short hh, ll; split_bf16(x, hh, ll);
          vh[(q << 2) + e] = hh;
          vl[(q << 2) + e] = ll;
        }
      }
      *(bf16x8*)&Yhi[row * S + c0 + (ch << 3)] = vh;
      *(bf16x8*)&Ylo[row * S + c0 + (ch << 3)] = vl;
    }
  }
  #pragma unroll
  for (int off = 32; off; off >>= 1) ss += __shfl_xor(ss, off, 64);
  if (lane == 0) red[wave] = ss;
  __syncthreads();
  float tot = 0.f;
  #pragma unroll
  for (int w = 0; w < 8; ++w) tot += red[w];
  const float normA = sqrtf(tot);
  const float rn    = 1.f / normA;
  const float s_out = sqrtf(normA);

  f32x4 accM[2][4];
  const f32x4 zero4 = {0.f, 0.f, 0.f, 0.f};

  #pragma unroll 1
  for (int it = 1; it <= 5; ++it) {
    const bool doQ = (it >= 2) && (it <= 4);   // it1: Z1 = T; it5: Z unused
    f32x4 accP[2][4];
    f32x4 accQ[2][4];
    #pragma unroll
    for (int i = 0; i < 2; ++i)
      #pragma unroll
      for (int j = 0; j < 4; ++j) { accP[i][j] = zero4; accQ[i][j] = zero4; }

    if (it == 1) {
      // M = Z0*Y0n; stored Y = A (unnormalized): accM = A slab (symmetric read)
      #pragma unroll
      for (int i = 0; i < 2; ++i)
        #pragma unroll
        for (int j = 0; j < 4; ++j) {
          const int col  = CB + 16*j + lrow;
          const int row0 = RB + 16*i + (quad << 2);
          short4v h = *(const short4v*)&Yhi[col * S + row0];
          short4v l = *(const short4v*)&Ylo[col * S + row0];
          #pragma unroll
          for (int r = 0; r < 4; ++r) accM[i][j][r] = bf2f(h[r]) + bf2f(l[r]);
        }
    } else {
      // M = Z*Y  (A = Z rows; B = Y rows via symmetry)
      #pragma unroll
      for (int i = 0; i < 2; ++i)
        #pragma unroll
        for (int j = 0; j < 4; ++j) accM[i][j] = zero4;
      #pragma unroll
      for (int kc = 0; kc < 4; ++kc) {
        const int k0 = (kc << 5) + (quad << 3);
        bf16x8 ah[2], al[2], bh[4], bl[4];
        #pragma unroll
        for (int i = 0; i < 2; ++i) {
          const int o = (RB + lrow + 16*i) * S + k0;
          ah[i] = *(const bf16x8*)&Zhi[o];
          al[i] = *(const bf16x8*)&Zlo[o];
        }
        #pragma unroll
        for (int j = 0; j < 4; ++j) {
          const int o = (CB + lrow + 16*j) * S + k0;
          bh[j] = *(const bf16x8*)&Yhi[o];
          bl[j] = *(const bf16x8*)&Ylo[o];
        }
        #pragma unroll
        for (int i = 0; i < 2; ++i)
          #pragma unroll
          for (int j = 0; j < 4; ++j) { MFMA3(accM[i][j], ah[i], al[i], bh[j], bl[j]); }
      }
    }

    // T = 1.5 I - 0.5 * mscale * M   (mscale folds the it==1 normalization)
    const float mscale = (it == 1) ? rn : 1.0f;
    #pragma unroll
    for (int i = 0; i < 2; ++i)
      #pragma unroll
      for (int j = 0; j < 4; ++j)
        #pragma unroll
        for (int r = 0; r < 4; ++r) {
          float tv = -0.5f * mscale * accM[i][j][r];
          if (RB + 16*i + (quad << 2) + r == CB + 16*j + lrow) tv += 1.5f;
          accM[i][j][r] = tv;
        }

    // 4 phases over 32-row blocks of T; waves with wr==t stage their slab
    // into Tq packed by column (T symmetric, so this IS T's column-slab).
    #pragma unroll
    for (int t = 0; t < 4; ++t) {
      __syncthreads();                     // Tq free from previous phase
      if (wr == t) {
        #pragma unroll
        for (int i = 0; i < 2; ++i) {
          const int kp0 = (i << 4) + (quad << 2);   // row0 - 32t
          #pragma unroll
          for (int j = 0; j < 4; ++j) {
            const int col = CB + 16*j + lrow;
            short4v h, l;
            #pragma unroll
            for (int r = 0; r < 4; ++r) {
              short hh, ll;
              split_bf16(accM[i][j][r], hh, ll);
              h[r] = hh; l[r] = ll;
            }
            *(short4v*)&Tqhi[col * SQ + kp0] = h;
            *(short4v*)&Tqlo[col * SQ + kp0] = l;
          }
        }
      }
      __syncthreads();
      {
        const int k0 = (t << 5) + (quad << 3);
        const int kq = quad << 3;
        bf16x8 bh[4], bl[4];
        // shared B-fragments: T column-slab
        #pragma unroll
        for (int j = 0; j < 4; ++j) {
          const int o = (CB + lrow + 16*j) * SQ + kq;
          bh[j] = *(const bf16x8*)&Tqhi[o];
          bl[j] = *(const bf16x8*)&Tqlo[o];
        }
        // P += Y[:,32t:+32] * T[32t:+32,:]
        {
          bf16x8 ah[2], al[2];
          #pragma unroll
          for (int i = 0; i < 2; ++i) {
            const int o = (RB + lrow + 16*i) * S + k0;
            ah[i] = *(const bf16x8*)&Yhi[o];
            al[i] = *(const bf16x8*)&Ylo[o];
          }
          #pragma unroll
          for (int i = 0; i < 2; ++i)
            #pragma unroll
            for (int j = 0; j < 4; ++j) { MFMA3(accP[i][j], ah[i], al[i], bh[j], bl[j]); }
        }
        // Q += Z[:,32t:+32] * T[32t:+32,:]   (Z*T == T*Z, commuting family)
        if (doQ) {
          bf16x8 ah[2], al[2];
          #pragma unroll
          for (int i = 0; i < 2; ++i) {
            const int o = (RB + lrow + 16*i) * S + k0;
            ah[i] = *(const bf16x8*)&Zhi[o];
            al[i] = *(const bf16x8*)&Zlo[o];
          }
          #pragma unroll
          for (int i = 0; i < 2; ++i)
            #pragma unroll
            for (int j = 0; j < 4; ++j) { MFMA3(accQ[i][j], ah[i], al[i], bh[j], bl[j]); }
        }
      }
    }
    __syncthreads();   // all reads of Y/Z/Tq complete

    if (it < 5) {
      // write-back (packed b64 "transposed" store = same matrix by symmetry)
      // it==1: true Y1 = rn * (A*T)  (normalization fold); Z1 = T.
      const float yscale = (it == 1) ? rn : 1.0f;
      #pragma unroll
      for (int i = 0; i < 2; ++i)
        #pragma unroll
        for (int j = 0; j < 4; ++j) {
          const int col  = CB + 16*j + lrow;
          const int row0 = RB + 16*i + (quad << 2);
          short4v h, l;
          #pragma unroll
          for (int r = 0; r < 4; ++r) {
            short hh, ll; split_bf16(yscale * accP[i][j][r], hh, ll);
            h[r] = hh; l[r] = ll;
          }
          *(short4v*)&Yhi[col * S + row0] = h;
          *(short4v*)&Ylo[col * S + row0] = l;
          #pragma unroll
          for (int r = 0; r < 4; ++r) {
            const float zv = (it == 1) ? accM[i][j][r] : accQ[i][j][r];
            short hh, ll; split_bf16(zv, hh, ll);
            h[r] = hh; l[r] = ll;
          }
          *(short4v*)&Zhi[col * S + row0] = h;
          *(short4v*)&Zlo[col * S + row0] = l;
        }
      __syncthreads();
    } else {
      // final: out = Y5 * sqrt(normA)
      float* ob = out + (size_t)b * (NN * NN);
      #pragma unroll
      for (int i = 0; i < 2; ++i)
        #pragma unroll
        for (int j = 0; j < 4; ++j) {
          const int col  = CB + 16*j + lrow;
          const int row0 = RB + 16*i + (quad << 2);
          #pragma unroll
          for (int r = 0; r < 4; ++r)
            ob[(size_t)(row0 + r) * NN + col] = accP[i][j][r] * s_out;
        }
    }
  }
}

extern "C" void kernel_launch(void* const* d_in, const int* in_sizes, int n_in,
                              void* d_out, int out_size, void* d_ws, size_t ws_size,
                              hipStream_t stream) {
  const float* A = (const float*)d_in[0];
  float* out = (float*)d_out;
  ns_sqrt_kernel<<<dim3(1024), dim3(512), 0, stream>>>(A, out);
}

// Round 4
// 330.120 us; speedup vs baseline: 1.1204x; 1.0012x over previous
//
#include <hip/hip_runtime.h>

// Newton-Schulz matrix sqrt, 1024 batches of 128x128 SPD, 5 iterations.
// R4 (stall reduction; layouts identical to R3):
//   - A-fragment (Y/Z) reads hoisted ABOVE the Tq staging barriers (no Tq dep)
//   - T pre-split into packed regs after the T-transform; staging = b64 writes
//   - trunc-hi + RNE-lo split (same 2^-17 total precision, ~half the VALU)
//   - t==0 "Tq free" barrier dropped (covered by post-loop + writeback syncs)
//   - 2 batches per block (grid 512): out-stores overlap next batch's init
// Model from R3 counters: ~80-100k of 162k cycles/block are barrier stalls;
// LDS pipe ~48k, MFMA ~14k/SIMD. WRITE_SIZE ~150 MB == output + harness poison
// (no spills; R2 spill theory was wrong).

#define NN 128
#define S  136   // row stride in shorts for Y/Z (pad 8: bank-balanced, 16B rows)
#define SQ 40    // row stride in shorts for Tq panel (32 + 8)

typedef short bf16x8  __attribute__((ext_vector_type(8)));
typedef short short4v __attribute__((ext_vector_type(4)));
typedef float f32x4   __attribute__((ext_vector_type(4)));

__device__ __forceinline__ float bf2f(short h) {
  union { unsigned u; float f; } c;
  c.u = ((unsigned)(unsigned short)h) << 16;
  return c.f;
}

__device__ __forceinline__ short f2bf_rne(float x) {
  union { float f; unsigned u; } c; c.f = x;
  unsigned u = c.u;
  return (short)((u + 0x7fffu + ((u >> 16) & 1u)) >> 16);
}

// hi = bit-truncated top 16 (error <= 2^-8|x|), lo = RNE(x - hi) (residual 2^-17|x|)
__device__ __forceinline__ void split_bf16(float x, short& h, short& l) {
  union { float f; unsigned u; } c; c.f = x;
  h = (short)(c.u >> 16);
  union { unsigned u; float f; } hf; hf.u = c.u & 0xFFFF0000u;
  l = f2bf_rne(x - hf.f);
}

__device__ __forceinline__ unsigned pack2(short a, short b) {
  return (unsigned)(unsigned short)a | ((unsigned)(unsigned short)b << 16);
}

#define MFMA3(ACC, AH, AL, BH, BL)                                        \
  ACC = __builtin_amdgcn_mfma_f32_16x16x32_bf16(AH, BH, ACC, 0, 0, 0);    \
  ACC = __builtin_amdgcn_mfma_f32_16x16x32_bf16(AH, BL, ACC, 0, 0, 0);    \
  ACC = __builtin_amdgcn_mfma_f32_16x16x32_bf16(AL, BH, ACC, 0, 0, 0);

__global__ __launch_bounds__(512, 1)
void ns_sqrt_kernel(const float* __restrict__ A, float* __restrict__ out) {
  __shared__ __align__(16) short Yhi[NN * S];
  __shared__ __align__(16) short Ylo[NN * S];
  __shared__ __align__(16) short Zhi[NN * S];
  __shared__ __align__(16) short Zlo[NN * S];
  __shared__ __align__(16) short Tqhi[NN * SQ];
  __shared__ __align__(16) short Tqlo[NN * SQ];
  __shared__ float red[8];

  const int tid  = threadIdx.x;
  const int wave = tid >> 6;
  const int lane = tid & 63;
  const int quad = lane >> 4;
  const int lrow = lane & 15;
  const int wr = wave >> 1, wc = wave & 1;
  const int RB = wr << 5, CB = wc << 6;   // 32x64 slab base

  #pragma unroll 1
  for (int sb = 0; sb < 2; ++sb) {
    const int b = (blockIdx.x << 1) + sb;
    const float* Ab = A + (size_t)b * (NN * NN);

    // ---- init: load all of A, Frobenius sum, store unnormalized split A ----
    float ss = 0.f;
    {
      const float4* p = reinterpret_cast<const float4*>(Ab);
      const int row = tid >> 2;          // 0..127
      const int c0  = (tid & 3) << 5;    // 0,32,64,96
      #pragma unroll
      for (int ch = 0; ch < 4; ++ch) {
        bf16x8 vh, vl;
        #pragma unroll
        for (int q = 0; q < 2; ++q) {
          float4 v = p[row * (NN / 4) + (c0 >> 2) + (ch << 1) + q];
          float xs[4] = {v.x, v.y, v.z, v.w};
          #pragma unroll
          for (int e = 0; e < 4; ++e) {
            float x = xs[e];
            ss += x * x;
            short hh, ll; split_bf16(x, hh, ll);
            vh[(q << 2) + e] = hh;
            vl[(q << 2) + e] = ll;
          }
        }
        *(bf16x8*)&Yhi[row * S + c0 + (ch << 3)] = vh;
        *(bf16x8*)&Ylo[row * S + c0 + (ch << 3)] = vl;
      }
    }
    #pragma unroll
    for (int off = 32; off; off >>= 1) ss += __shfl_xor(ss, off, 64);
    if (lane == 0) red[wave] = ss;
    __syncthreads();
    float tot = 0.f;
    #pragma unroll
    for (int w = 0; w < 8; ++w) tot += red[w];
    const float normA = sqrtf(tot);
    const float rn    = 1.f / normA;
    const float s_out = sqrtf(normA);

    const f32x4 zero4 = {0.f, 0.f, 0.f, 0.f};

    #pragma unroll 1
    for (int it = 1; it <= 5; ++it) {
      const bool doQ = (it >= 2) && (it <= 4);   // it1: Z1 = T; it5: Z unused
      f32x4 accM[2][4];
      f32x4 accP[2][4];
      f32x4 accQ[2][4];
      #pragma unroll
      for (int i = 0; i < 2; ++i)
        #pragma unroll
        for (int j = 0; j < 4; ++j) { accP[i][j] = zero4; accQ[i][j] = zero4; }

      if (it == 1) {
        // M = A slab (symmetric b64 read); normalization folded via mscale
        #pragma unroll
        for (int i = 0; i < 2; ++i)
          #pragma unroll
          for (int j = 0; j < 4; ++j) {
            const int col  = CB + 16*j + lrow;
            const int row0 = RB + 16*i + (quad << 2);
            short4v h = *(const short4v*)&Yhi[col * S + row0];
            short4v l = *(const short4v*)&Ylo[col * S + row0];
            #pragma unroll
            for (int r = 0; r < 4; ++r) accM[i][j][r] = bf2f(h[r]) + bf2f(l[r]);
          }
      } else {
        // M = Z*Y  (A = Z rows; B = Y rows via symmetry)
        #pragma unroll
        for (int i = 0; i < 2; ++i)
          #pragma unroll
          for (int j = 0; j < 4; ++j) accM[i][j] = zero4;
        #pragma unroll
        for (int kc = 0; kc < 4; ++kc) {
          const int k0 = (kc << 5) + (quad << 3);
          bf16x8 ah[2], al[2], bh[4], bl[4];
          #pragma unroll
          for (int i = 0; i < 2; ++i) {
            const int o = (RB + lrow + 16*i) * S + k0;
            ah[i] = *(const bf16x8*)&Zhi[o];
            al[i] = *(const bf16x8*)&Zlo[o];
          }
          #pragma unroll
          for (int j = 0; j < 4; ++j) {
            const int o = (CB + lrow + 16*j) * S + k0;
            bh[j] = *(const bf16x8*)&Yhi[o];
            bl[j] = *(const bf16x8*)&Ylo[o];
          }
          #pragma unroll
          for (int i = 0; i < 2; ++i)
            #pragma unroll
            for (int j = 0; j < 4; ++j) { MFMA3(accM[i][j], ah[i], al[i], bh[j], bl[j]); }
        }
      }

      // T = 1.5 I - 0.5*mscale*M, split immediately into packed regs
      // (staging then = pure b64 writes; accM dead afterwards)
      const float mscale = (it == 1) ? rn : 1.0f;
      unsigned tp[2][4][2], tl[2][4][2];
      #pragma unroll
      for (int i = 0; i < 2; ++i)
        #pragma unroll
        for (int j = 0; j < 4; ++j) {
          short h[4], l[4];
          #pragma unroll
          for (int r = 0; r < 4; ++r) {
            float tv = -0.5f * mscale * accM[i][j][r];
            if (RB + 16*i + (quad << 2) + r == CB + 16*j + lrow) tv += 1.5f;
            split_bf16(tv, h[r], l[r]);
          }
          tp[i][j][0] = pack2(h[0], h[1]); tp[i][j][1] = pack2(h[2], h[3]);
          tl[i][j][0] = pack2(l[0], l[1]); tl[i][j][1] = pack2(l[2], l[3]);
        }

      // 4 phases over 32-row blocks of T; waves wr==t stage from packed regs.
      #pragma unroll 1
      for (int t = 0; t < 4; ++t) {
        // A-fragments depend only on Y/Z (stable all phase-loop long):
        // issue BEFORE the barriers so their latency hides staging.
        const int k0 = (t << 5) + (quad << 3);
        bf16x8 ahY[2], alY[2], ahZ[2], alZ[2];
        #pragma unroll
        for (int i = 0; i < 2; ++i) {
          const int o = (RB + lrow + 16*i) * S + k0;
          ahY[i] = *(const bf16x8*)&Yhi[o];
          alY[i] = *(const bf16x8*)&Ylo[o];
        }
        if (doQ) {
          #pragma unroll
          for (int i = 0; i < 2; ++i) {
            const int o = (RB + lrow + 16*i) * S + k0;
            ahZ[i] = *(const bf16x8*)&Zhi[o];
            alZ[i] = *(const bf16x8*)&Zlo[o];
          }
        }

        if (t) __syncthreads();            // Tq consumed by all (skip at t==0:
                                           // covered by post-loop+writeback syncs)
        if (wr == t) {
          #pragma unroll
          for (int i = 0; i < 2; ++i) {
            const int kp0 = (i << 4) + (quad << 2);
            #pragma unroll
            for (int j = 0; j < 4; ++j) {
              const int col = CB + 16*j + lrow;
              *(uint2*)&Tqhi[col * SQ + kp0] = make_uint2(tp[i][j][0], tp[i][j][1]);
              *(uint2*)&Tqlo[col * SQ + kp0] = make_uint2(tl[i][j][0], tl[i][j][1]);
            }
          }
        }
        __syncthreads();                   // Tq ready

        const int kq = quad << 3;
        bf16x8 bh[4], bl[4];
        #pragma unroll
        for (int j = 0; j < 4; ++j) {
          const int o = (CB + lrow + 16*j) * SQ + kq;
          bh[j] = *(const bf16x8*)&Tqhi[o];
          bl[j] = *(const bf16x8*)&Tqlo[o];
        }
        #pragma unroll
        for (int i = 0; i < 2; ++i)
          #pragma unroll
          for (int j = 0; j < 4; ++j) { MFMA3(accP[i][j], ahY[i], alY[i], bh[j], bl[j]); }
        if (doQ) {
          #pragma unroll
          for (int i = 0; i < 2; ++i)
            #pragma unroll
            for (int j = 0; j < 4; ++j) { MFMA3(accQ[i][j], ahZ[i], alZ[i], bh[j], bl[j]); }
        }
      }
      __syncthreads();   // all reads of Y/Z/Tq complete

      if (it < 5) {
        // write-back (packed b64 "transposed" store = same matrix by symmetry)
        const float yscale = (it == 1) ? rn : 1.0f;
        #pragma unroll
        for (int i = 0; i < 2; ++i)
          #pragma unroll
          for (int j = 0; j < 4; ++j) {
            const int col  = CB + 16*j + lrow;
            const int row0 = RB + 16*i + (quad << 2);
            short h[4], l[4];
            #pragma unroll
            for (int r = 0; r < 4; ++r) split_bf16(yscale * accP[i][j][r], h[r], l[r]);
            *(uint2*)&Yhi[col * S + row0] = make_uint2(pack2(h[0], h[1]), pack2(h[2], h[3]));
            *(uint2*)&Ylo[col * S + row0] = make_uint2(pack2(l[0], l[1]), pack2(l[2], l[3]));
            if (it == 1) {
              // Z1 = T: reuse the packed split regs directly
              *(uint2*)&Zhi[col * S + row0] = make_uint2(tp[i][j][0], tp[i][j][1]);
              *(uint2*)&Zlo[col * S + row0] = make_uint2(tl[i][j][0], tl[i][j][1]);
            } else {
              #pragma unroll
              for (int r = 0; r < 4; ++r) split_bf16(accQ[i][j][r], h[r], l[r]);
              *(uint2*)&Zhi[col * S + row0] = make_uint2(pack2(h[0], h[1]), pack2(h[2], h[3]));
              *(uint2*)&Zlo[col * S + row0] = make_uint2(pack2(l[0], l[1]), pack2(l[2], l[3]));
            }
          }
        __syncthreads();
      } else {
        // final: out = Y5 * sqrt(normA)  (fire-and-forget; overlaps next init)
        float* ob = out + (size_t)b * (NN * NN);
        #pragma unroll
        for (int i = 0; i < 2; ++i)
          #pragma unroll
          for (int j = 0; j < 4; ++j) {
            const int col  = CB + 16*j + lrow;
            const int row0 = RB + 16*i + (quad << 2);
            #pragma unroll
            for (int r = 0; r < 4; ++r)
              ob[(size_t)(row0 + r) * NN + col] = accP[i][j][r] * s_out;
          }
      }
    }
  }
}

extern "C" void kernel_launch(void* const* d_in, const int* in_sizes, int n_in,
                              void* d_out, int out_size, void* d_ws, size_t ws_size,
                              hipStream_t stream) {
  const float* A = (const float*)d_in[0];
  float* out = (float*)d_out;
  ns_sqrt_kernel<<<dim3(512), dim3(512), 0, stream>>>(A, out);
}